// Round 2
// 1940.860 us; speedup vs baseline: 1.0463x; 1.0463x over previous
//
#include <hip/hip_runtime.h>
#include <math.h>

// OnlineClustering: x[4,4096,768] f32, W[8192,768] f32
// out = assignments[4,4096,8192] f32 ++ loss[1] f32
//
// R3b: per-s scheduling (128 MB logits slice stays Infinity-Cache resident
//     across all Sinkhorn passes), colmax fused into GEMM epilogue
//     (orderable-uint atomicMax), float4 column/row passes, NT out-stores.
//     GEMM inner loop unchanged from R2 (split-bf16, m97 structure).
//     (R3 fix: NT store uses clang ext_vector f32x4, not HIP float4.)

#define S_DIM 4
#define B_DIM 4096
#define D_DIM 768
#define K_DIM 8192
#define ROWS (S_DIM * B_DIM)   // 16384
#define PB_ROWS 64
#define PB_CHUNKS (B_DIM / PB_ROWS)  // 64
#define SK_EPS 1e-8f

typedef unsigned short ushort_t;
typedef __attribute__((ext_vector_type(8))) short short8;
typedef __attribute__((ext_vector_type(4))) float f32x4;

__device__ __forceinline__ ushort_t f2bf_rne(float f) {
  union { float f; unsigned u; } c; c.f = f;
  unsigned u = c.u;
  unsigned r = u + 0x7FFFu + ((u >> 16) & 1u);
  return (ushort_t)(r >> 16);
}
__device__ __forceinline__ float bf2f(ushort_t h) {
  union { unsigned u; float f; } c; c.u = ((unsigned)h) << 16;
  return c.f;
}

// orderable-uint encoding for float atomicMax (all-real inputs)
__device__ __forceinline__ unsigned fenc(float f) {
  unsigned u = __float_as_uint(f);
  return (u & 0x80000000u) ? ~u : (u | 0x80000000u);
}
__device__ __forceinline__ float fdec(unsigned u) {
  u = (u & 0x80000000u) ? (u & 0x7fffffffu) : ~u;
  return __uint_as_float(u);
}

__device__ __forceinline__ float block_reduce_sum(float v, float* sbuf) {
  #pragma unroll
  for (int off = 32; off > 0; off >>= 1) v += __shfl_down(v, off, 64);
  int lane = threadIdx.x & 63, wid = threadIdx.x >> 6;
  __syncthreads();
  if (lane == 0) sbuf[wid] = v;
  __syncthreads();
  return sbuf[0] + sbuf[1] + sbuf[2] + sbuf[3];
}

__device__ __forceinline__ float block_reduce_max(float v, float* sbuf) {
  #pragma unroll
  for (int off = 32; off > 0; off >>= 1) v = fmaxf(v, __shfl_down(v, off, 64));
  int lane = threadIdx.x & 63, wid = threadIdx.x >> 6;
  __syncthreads();
  if (lane == 0) sbuf[wid] = v;
  __syncthreads();
  return fmaxf(fmaxf(sbuf[0], sbuf[1]), fmaxf(sbuf[2], sbuf[3]));
}

// ---------------- K0a: L2-normalize rows of x, emit bf16 hi/lo split ----------------
__global__ __launch_bounds__(256) void normalize_split(const float* __restrict__ x,
                                                       ushort_t* __restrict__ Ahi,
                                                       ushort_t* __restrict__ Alo) {
  __shared__ float sbuf[4];
  size_t row = blockIdx.x;
  const float* xr = x + row * D_DIM;
  float ss = 0.f;
  for (int i = threadIdx.x; i < D_DIM; i += 256) { float v = xr[i]; ss += v * v; }
  ss = block_reduce_sum(ss, sbuf);
  float inv = 1.0f / fmaxf(sqrtf(ss), 1e-7f);
  for (int i = threadIdx.x; i < D_DIM; i += 256) {
    float v = xr[i] * inv;
    ushort_t h = f2bf_rne(v);
    Ahi[row * D_DIM + i] = h;
    Alo[row * D_DIM + i] = f2bf_rne(v - bf2f(h));
  }
}

// ---------------- K0b: bf16 hi/lo split of W ----------------
__global__ __launch_bounds__(256) void split_w(const float* __restrict__ W,
                                               ushort_t* __restrict__ Whi,
                                               ushort_t* __restrict__ Wlo, int n4) {
  int i = blockIdx.x * 256 + threadIdx.x;
  if (i >= n4) return;
  float4 wv = ((const float4*)W)[i];
  float v[4] = {wv.x, wv.y, wv.z, wv.w};
  ushort4 h, l;
  ushort_t hh[4], ll[4];
  #pragma unroll
  for (int c = 0; c < 4; c++) {
    hh[c] = f2bf_rne(v[c]);
    ll[c] = f2bf_rne(v[c] - bf2f(hh[c]));
  }
  h.x = hh[0]; h.y = hh[1]; h.z = hh[2]; h.w = hh[3];
  l.x = ll[0]; l.y = ll[1]; l.z = ll[2]; l.w = ll[3];
  ((ushort4*)Whi)[i] = h;
  ((ushort4*)Wlo)[i] = l;
}

// ---------------- K1: MFMA GEMM  C[4096,8192] = A_s[4096,768] * W[8192,768]^T ---------
// BM=BN=128, BK=32, 256 threads (4 waves, 2x2 of 64x64), 16x16x32 bf16 MFMA.
// Epilogue also accumulates per-column max into maxs[] (orderable atomicMax).
__global__ __launch_bounds__(256, 2) void gemm_mfma(const ushort_t* __restrict__ Ahi,
                                                    const ushort_t* __restrict__ Alo,
                                                    const ushort_t* __restrict__ Bhi,
                                                    const ushort_t* __restrict__ Blo,
                                                    float* __restrict__ C,
                                                    unsigned* __restrict__ maxs) {
  __shared__ __align__(16) ushort_t sAhi[128 * 32];
  __shared__ __align__(16) ushort_t sAlo[128 * 32];
  __shared__ __align__(16) ushort_t sBhi[128 * 32];
  __shared__ __align__(16) ushort_t sBlo[128 * 32];

  const int tid = threadIdx.x;
  const int w = tid >> 6, lane = tid & 63;

  // block swizzle: groups of 8 M-blocks sweep all N for L2 reuse
  int bid = blockIdx.y * gridDim.x + blockIdx.x;
  int grp = bid / (8 * 64);
  int rem = bid % (8 * 64);
  int by = grp * 8 + (rem & 7);
  int bx = rem >> 3;
  const int bm = by * 128, bn = bx * 128;
  const int wm = (w >> 1) * 64, wn = (w & 1) * 64;

  f32x4 acc[4][4] = {};

  // staging: per wave, per array, 2 calls of 16 rows x 32 k (1 KB each)
  const int srow = w * 32 + (lane >> 2);     // + c*16
  const int skof = (lane & 3) * 8;
  const size_t gAbase = (size_t)(bm + srow) * D_DIM + skof;
  const size_t gBbase = (size_t)(bn + srow) * D_DIM + skof;

  // loop-invariant fragment LDS offsets (elements)
  const int q8 = (lane >> 4) * 8;
  int aoff[4], boff[4];
  #pragma unroll
  for (int i = 0; i < 4; i++) aoff[i] = (wm + i * 16 + (lane & 15)) * 32 + q8;
  #pragma unroll
  for (int j = 0; j < 4; j++) boff[j] = (wn + j * 16 + (lane & 15)) * 32 + q8;

  for (int k0 = 0; k0 < D_DIM; k0 += 32) {
    #pragma unroll
    for (int c = 0; c < 2; c++) {
      const int lofs = (w * 32 + c * 16) * 32;
      const size_t go = (size_t)c * 16 * D_DIM + k0;
      __builtin_amdgcn_global_load_lds(
          (const __attribute__((address_space(1))) void*)(Ahi + gAbase + go),
          (__attribute__((address_space(3))) void*)(sAhi + lofs), 16, 0, 0);
      __builtin_amdgcn_global_load_lds(
          (const __attribute__((address_space(1))) void*)(Alo + gAbase + go),
          (__attribute__((address_space(3))) void*)(sAlo + lofs), 16, 0, 0);
      __builtin_amdgcn_global_load_lds(
          (const __attribute__((address_space(1))) void*)(Bhi + gBbase + go),
          (__attribute__((address_space(3))) void*)(sBhi + lofs), 16, 0, 0);
      __builtin_amdgcn_global_load_lds(
          (const __attribute__((address_space(1))) void*)(Blo + gBbase + go),
          (__attribute__((address_space(3))) void*)(sBlo + lofs), 16, 0, 0);
    }
    __syncthreads();

    short8 ah[4], al[4], bh[4], bl[4];
    #pragma unroll
    for (int i = 0; i < 4; i++) {
      ah[i] = *(const short8*)(sAhi + aoff[i]);
      al[i] = *(const short8*)(sAlo + aoff[i]);
    }
    #pragma unroll
    for (int j = 0; j < 4; j++) {
      bh[j] = *(const short8*)(sBhi + boff[j]);
      bl[j] = *(const short8*)(sBlo + boff[j]);
    }
    #pragma unroll
    for (int i = 0; i < 4; i++)
      #pragma unroll
      for (int j = 0; j < 4; j++) {
        acc[i][j] = __builtin_amdgcn_mfma_f32_16x16x32_bf16(ah[i], bh[j], acc[i][j], 0, 0, 0);
        acc[i][j] = __builtin_amdgcn_mfma_f32_16x16x32_bf16(ah[i], bl[j], acc[i][j], 0, 0, 0);
        acc[i][j] = __builtin_amdgcn_mfma_f32_16x16x32_bf16(al[i], bh[j], acc[i][j], 0, 0, 0);
      }
    __syncthreads();
  }

  // epilogue: C/D layout col=lane&15, row=(lane>>4)*4+reg
  const int col0 = bn + wn + (lane & 15);
  const int row0 = bm + wm + (lane >> 4) * 4;
  #pragma unroll
  for (int i = 0; i < 4; i++)
    #pragma unroll
    for (int r = 0; r < 4; r++) {
      size_t rowoff = (size_t)(row0 + i * 16 + r) * K_DIM;
      #pragma unroll
      for (int j = 0; j < 4; j++)
        C[rowoff + col0 + j * 16] = acc[i][j][r];
    }

  // fused column-max: per-lane max over 16 rows, butterfly over row-groups,
  // then one atomicMax per (wave, column).
  float m4[4];
  #pragma unroll
  for (int j = 0; j < 4; j++) {
    float m = -INFINITY;
    #pragma unroll
    for (int i = 0; i < 4; i++)
      #pragma unroll
      for (int r = 0; r < 4; r++) m = fmaxf(m, acc[i][j][r]);
    m = fmaxf(m, __shfl_xor(m, 16, 64));
    m = fmaxf(m, __shfl_xor(m, 32, 64));
    m4[j] = m;
  }
  if ((lane >> 4) == 0) {
    #pragma unroll
    for (int j = 0; j < 4; j++)
      atomicMax(maxs + bn + wn + j * 16 + (lane & 15), fenc(m4[j]));
  }
}

// ---------------- convert per-column max to exp offset ----------------
__global__ __launch_bounds__(256) void off_convert(const unsigned* __restrict__ mb,
                                                   float* __restrict__ offv) {
  int k = blockIdx.x * 256 + threadIdx.x;
  offv[k] = 50.0f - 20.0f * fdec(mb[k]);
}

// ---------------- column sum partials: sum_b E * (RS[b] or 1) ----------------
// float4 per thread (4 consecutive k), 64 rows per chunk.
__global__ __launch_bounds__(256) void col_sum_partial(const float* __restrict__ logits,
                                                       const float* __restrict__ offv,
                                                       const float* __restrict__ RS, int use_rs,
                                                       float* __restrict__ pbuf) {
  int k4 = blockIdx.x * 256 + threadIdx.x;   // gridDim.x = K/1024 = 8
  int chunk = blockIdx.y;
  const float4 off = ((const float4*)offv)[k4];
  const float* base = logits + (size_t)(chunk * PB_ROWS) * K_DIM + (size_t)k4 * 4;
  const float* rs = RS + chunk * PB_ROWS;
  float sx = 0.f, sy = 0.f, sz = 0.f, sw = 0.f;
  #pragma unroll 8
  for (int b = 0; b < PB_ROWS; b++) {
    float4 lv = *(const float4*)(base + (size_t)b * K_DIM);
    float rfac = use_rs ? rs[b] : 1.0f;
    sx += __expf(fmaf(20.0f, lv.x, off.x)) * rfac;
    sy += __expf(fmaf(20.0f, lv.y, off.y)) * rfac;
    sz += __expf(fmaf(20.0f, lv.z, off.z)) * rfac;
    sw += __expf(fmaf(20.0f, lv.w, off.w)) * rfac;
  }
  float4 o = {sx, sy, sz, sw};
  ((float4*)pbuf)[(size_t)chunk * (K_DIM / 4) + k4] = o;
}

__global__ __launch_bounds__(256) void col_sum_reduce(const float* __restrict__ pbuf,
                                                      float* __restrict__ CS, int init) {
  int k4 = blockIdx.x * 256 + threadIdx.x;   // gridDim.x = K/1024 = 8
  float sx = 0.f, sy = 0.f, sz = 0.f, sw = 0.f;
  #pragma unroll 8
  for (int c = 0; c < PB_CHUNKS; c++) {
    float4 v = ((const float4*)pbuf)[(size_t)c * (K_DIM / 4) + k4];
    sx += v.x; sy += v.y; sz += v.z; sw += v.w;
  }
  float4 old = init ? (float4){1.f, 1.f, 1.f, 1.f} : ((const float4*)CS)[k4];
  float4 o;
  o.x = old.x / fmaf(old.x, sx, SK_EPS);
  o.y = old.y / fmaf(old.y, sy, SK_EPS);
  o.z = old.z / fmaf(old.z, sz, SK_EPS);
  o.w = old.w / fmaf(old.w, sw, SK_EPS);
  ((float4*)CS)[k4] = o;
}

// ---------------- row pass (float4 over k) ----------------
__global__ __launch_bounds__(256) void row_pass(const float* __restrict__ logits,
                                                const float* __restrict__ offv,
                                                const float* __restrict__ CS,
                                                float* __restrict__ RS, int init) {
  __shared__ float sbuf[4];
  int b = blockIdx.x;
  const float* lg = logits + (size_t)b * K_DIM;
  const int t = threadIdx.x;
  float sum = 0.f;
  #pragma unroll
  for (int i = 0; i < 8; i++) {
    int k4 = i * 256 + t;
    float4 lv = ((const float4*)lg)[k4];
    float4 ov = ((const float4*)offv)[k4];
    float4 cv = ((const float4*)CS)[k4];
    sum += __expf(fmaf(20.0f, lv.x, ov.x)) * cv.x;
    sum += __expf(fmaf(20.0f, lv.y, ov.y)) * cv.y;
    sum += __expf(fmaf(20.0f, lv.z, ov.z)) * cv.z;
    sum += __expf(fmaf(20.0f, lv.w, ov.w)) * cv.w;
  }
  sum = block_reduce_sum(sum, sbuf);
  if (t == 0) {
    float old = init ? 1.0f : RS[b];
    RS[b] = old / fmaf(old, sum, SK_EPS);
  }
}

// ---------------- final: r3 + write assignments + loss (single logits read) ----------
__global__ __launch_bounds__(256) void final_pass(const float* __restrict__ logits,
                                                  const float* __restrict__ offv,
                                                  const float* __restrict__ CS,
                                                  const float* __restrict__ RS,
                                                  float* __restrict__ out,
                                                  double* __restrict__ loss_acc) {
  __shared__ float sbuf[4];
  int b = blockIdx.x;
  const float* lg = logits + (size_t)b * K_DIM;
  const int t = threadIdx.x;

  float v[32], ecs[32];
  float sum = 0.f, mx = -INFINITY;
  #pragma unroll
  for (int i = 0; i < 8; i++) {
    float4 lv = *(const float4*)&lg[t * 4 + i * 1024];
    float4 ov = *(const float4*)&offv[t * 4 + i * 1024];
    float4 cv = *(const float4*)&CS[t * 4 + i * 1024];
    float vv[4] = {lv.x, lv.y, lv.z, lv.w};
    float oo[4] = {ov.x, ov.y, ov.z, ov.w};
    float cc[4] = {cv.x, cv.y, cv.z, cv.w};
    #pragma unroll
    for (int c = 0; c < 4; c++) {
      v[i * 4 + c] = vv[c];
      float e = __expf(fmaf(20.0f, vv[c], oo[c])) * cc[c];
      ecs[i * 4 + c] = e;
      sum += e;
      mx = fmaxf(mx, vv[c]);
    }
  }
  sum = block_reduce_sum(sum, sbuf);
  mx = block_reduce_max(mx, sbuf);

  float r = RS[b];
  float rowsum = r * sum;
  float r3 = 1.0f / (rowsum + SK_EPS);
  float fac = r * r3;
  float sumtgt = rowsum * r3;
  const float qs = 1.0f / 0.12f;

  float Z = 0.f, dot = 0.f;
  float* orow = out + (size_t)b * K_DIM;
  #pragma unroll
  for (int i = 0; i < 8; i++) {
    float m4[4];
    #pragma unroll
    for (int c = 0; c < 4; c++) {
      float M = ecs[i * 4 + c] * fac;
      m4[c] = M;
      Z += __expf((v[i * 4 + c] - mx) * qs);
      dot += M * (v[i * 4 + c] * qs);
    }
    f32x4 o = {m4[0], m4[1], m4[2], m4[3]};
    // NT store: keep the out-stream from evicting the L3-resident logits slice
    __builtin_nontemporal_store(o, (f32x4*)&orow[t * 4 + i * 1024]);
  }
  Z = block_reduce_sum(Z, sbuf);
  dot = block_reduce_sum(dot, sbuf);
  if (t == 0) {
    float lossr = -(dot - sumtgt * (mx * qs + logf(Z)));
    atomicAdd(loss_acc, (double)lossr);
  }
}

__global__ void finalize_loss(const double* __restrict__ loss_acc, float* __restrict__ out_loss) {
  if (threadIdx.x == 0 && blockIdx.x == 0)
    *out_loss = (float)(*loss_acc / (double)ROWS);
}

extern "C" void kernel_launch(void* const* d_in, const int* in_sizes, int n_in,
                              void* d_out, int out_size, void* d_ws, size_t ws_size,
                              hipStream_t stream) {
  const float* x = (const float*)d_in[0];
  const float* W = (const float*)d_in[1];
  float* out = (float*)d_out;
  char* ws = (char*)d_ws;

  // ws layout (one reused per-s logits slice: 4096 x 8192 f32 = 128 MiB)
  float* logits = (float*)ws;
  char* p = ws + (size_t)B_DIM * K_DIM * 4;                       // 134,217,728
  ushort_t* Ahi = (ushort_t*)p;  p += (size_t)ROWS * D_DIM * 2;   // 25,165,824
  ushort_t* Alo = (ushort_t*)p;  p += (size_t)ROWS * D_DIM * 2;
  ushort_t* Whi = (ushort_t*)p;  p += (size_t)K_DIM * D_DIM * 2;  // 12,582,912
  ushort_t* Wlo = (ushort_t*)p;  p += (size_t)K_DIM * D_DIM * 2;
  unsigned* maxb = (unsigned*)p; p += (size_t)S_DIM * K_DIM * 4;
  float* offv = (float*)p;       p += (size_t)S_DIM * K_DIM * 4;
  float* CS   = (float*)p;       p += (size_t)S_DIM * K_DIM * 4;
  float* RS   = (float*)p;       p += (size_t)ROWS * 4;
  float* pbuf = (float*)p;       p += (size_t)PB_CHUNKS * K_DIM * 4;  // 2 MiB
  double* loss_acc = (double*)p;

  hipMemsetAsync(loss_acc, 0, sizeof(double), stream);
  // key 0 decodes below any real float -> valid "-inf" init for orderable atomicMax
  hipMemsetAsync(maxb, 0, (size_t)S_DIM * K_DIM * 4, stream);

  normalize_split<<<ROWS, 256, 0, stream>>>(x, Ahi, Alo);
  split_w<<<(K_DIM * D_DIM / 4 + 255) / 256, 256, 0, stream>>>(W, Whi, Wlo, K_DIM * D_DIM / 4);

  dim3 gg(K_DIM / 128, B_DIM / 128);  // (64, 32) per s
  dim3 gc(K_DIM / 1024, PB_CHUNKS);   // (8, 64)
  dim3 gcr(K_DIM / 1024);             // 8
  dim3 goc(K_DIM / 256);              // 32

  for (int s = 0; s < S_DIM; s++) {
    const ushort_t* Ahi_s = Ahi + (size_t)s * B_DIM * D_DIM;
    const ushort_t* Alo_s = Alo + (size_t)s * B_DIM * D_DIM;
    unsigned* maxb_s = maxb + (size_t)s * K_DIM;
    float* offv_s = offv + (size_t)s * K_DIM;
    float* CS_s = CS + (size_t)s * K_DIM;
    float* RS_s = RS + (size_t)s * B_DIM;
    float* out_s = out + (size_t)s * B_DIM * K_DIM;

    gemm_mfma<<<gg, 256, 0, stream>>>(Ahi_s, Alo_s, Whi, Wlo, logits, maxb_s);
    off_convert<<<goc, 256, 0, stream>>>(maxb_s, offv_s);

    // c1
    col_sum_partial<<<gc, 256, 0, stream>>>(logits, offv_s, RS_s, 0, pbuf);
    col_sum_reduce<<<gcr, 256, 0, stream>>>(pbuf, CS_s, 1);
    // r1
    row_pass<<<B_DIM, 256, 0, stream>>>(logits, offv_s, CS_s, RS_s, 1);
    // c2
    col_sum_partial<<<gc, 256, 0, stream>>>(logits, offv_s, RS_s, 1, pbuf);
    col_sum_reduce<<<gcr, 256, 0, stream>>>(pbuf, CS_s, 0);
    // r2
    row_pass<<<B_DIM, 256, 0, stream>>>(logits, offv_s, CS_s, RS_s, 0);
    // c3
    col_sum_partial<<<gc, 256, 0, stream>>>(logits, offv_s, RS_s, 1, pbuf);
    col_sum_reduce<<<gcr, 256, 0, stream>>>(pbuf, CS_s, 0);
    // r3 + outputs + loss
    final_pass<<<B_DIM, 256, 0, stream>>>(logits, offv_s, CS_s, RS_s, out_s, loss_acc);
  }

  finalize_loss<<<1, 64, 0, stream>>>(loss_acc, out + (out_size - 1));
}